// Round 1
// baseline (1120.290 us; speedup 1.0000x reference)
//
#include <hip/hip_runtime.h>

typedef _Float16 half8 __attribute__((ext_vector_type(8)));
typedef float floatx4 __attribute__((ext_vector_type(4)));

#define B_TOT 65536
#define K_TOT 1024
#define D_TOT 256

// d_out offsets (float elements), concatenated reference outputs:
// quantized(B*D), vq_loss(1), entropy(1), hard_inds(B), hard_q(B*D), enc_inds(B*K), cluster(1)
#define OFF_Q    0
#define OFF_LOSS 16777216
#define OFF_ENT  16777217
#define OFF_IDX  16777218
#define OFF_HQ   16842754
#define OFF_P    33619970
#define OFF_CM   100728834

// ws offsets (bytes); total ~1.85 MB
#define WS_E16   0          // K*D fp16        (512 KB)
#define WS_ETB   524288     // E^T tiled fp16: [kt][d][kl] 32x256x32 (512 KB)
#define WS_E2    1048576    // K floats
#define WS_INV   1052672    // B floats (1/rowsum)
#define WS_MIND  1314816    // B floats (row min dist)
#define WS_FLAG  1576960    // B ints (flagged row list)
#define WS_CNT   1839104    // int counter
#define WS_LSUM  1839108    // float loss sum
#define WS_CSUM  1839112    // float cluster sum
#define WS_COL   1839120    // 1024 floats col sums

#define THETA 1e-4f

// exact replica of numpy pairwise_sum for n=128 (<= blocksize): 8 accumulators
__device__ __forceinline__ float np_pw128(const float* a) {
  float r0=a[0],r1=a[1],r2=a[2],r3=a[3],r4=a[4],r5=a[5],r6=a[6],r7=a[7];
  for (int i = 8; i < 128; i += 8) {
    r0+=a[i+0]; r1+=a[i+1]; r2+=a[i+2]; r3+=a[i+3];
    r4+=a[i+4]; r5+=a[i+5]; r6+=a[i+6]; r7+=a[i+7];
  }
  return ((r0+r1)+(r2+r3))+((r4+r5)+(r6+r7));
}

__global__ void vq_prep(const float* __restrict__ emb, char* ws) {
  _Float16* E16 = (_Float16*)(ws + WS_E16);
  _Float16* ETb = (_Float16*)(ws + WS_ETB);
  float* e2g = (float*)(ws + WS_E2);
  int k = blockIdx.x, d = threadIdx.x;
  float v = emb[k*256 + d];
  E16[k*256 + d] = (_Float16)v;
  // tiled E^T: tile kt=k>>5 holds [d][k&31], contiguous 16KB per tile
  ETb[(k>>5)*8192 + d*32 + (k&31)] = (_Float16)v;
  __shared__ float sq[256];
  sq[d] = v*v;
  __syncthreads();
  if (d == 0) e2g[k] = np_pw128(sq) + np_pw128(sq+128);
  if (blockIdx.x == 0) {
    float* col = (float*)(ws + WS_COL);
    col[d] = 0.f; col[256+d] = 0.f; col[512+d] = 0.f; col[768+d] = 0.f;
    if (d == 0) {
      *(int*)(ws + WS_CNT) = 0;
      *(float*)(ws + WS_LSUM) = 0.f;
      *(float*)(ws + WS_CSUM) = 0.f;
    }
  }
}

// main fused kernel: 64 rows per block, 256 threads (4 waves), K in 32-col tiles.
// GEMM1: S = L * E^T (A-frags in registers), epilogue: v=e2-2dot, exp, min/sum,
// write ptilde (fp32, unnormalized) + fp16 A-buf; GEMM2: O += Ptile * Etile.
__global__ __launch_bounds__(256, 2) void vq_main(const float* __restrict__ latents,
                                                  char* ws, float* __restrict__ dout) {
  const _Float16* E16 = (const _Float16*)(ws + WS_E16);
  const _Float16* ETb = (const _Float16*)(ws + WS_ETB);
  const float* e2g = (const float*)(ws + WS_E2);
  float* invg = (float*)(ws + WS_INV);
  float* mindg = (float*)(ws + WS_MIND);
  int* flag = (int*)(ws + WS_FLAG);
  int* cnt = (int*)(ws + WS_CNT);
  float* lsum = (float*)(ws + WS_LSUM);
  float* csum = (float*)(ws + WS_CSUM);

  // swizzled LDS tiles (16B-chunk XOR swizzles; no padding needed)
  __shared__ _Float16 ldsE[32*256];   // [r][d], chunk' = chunk ^ r
  __shared__ _Float16 ldsET[256*32];  // [d][kl], chunk' = chunk ^ ((d>>1)&3)
  __shared__ _Float16 ldsA[64*32];    // [row][kl], chunk' = chunk ^ ((row>>1)&3)
  __shared__ float lds_e2[32];
  __shared__ float lds_inv[64];
  __shared__ float lds_red[4];

  int tid = threadIdx.x;
  int wave = tid >> 6, lane = tid & 63;
  int l15 = lane & 15, quad = lane >> 4;
  int blk = blockIdx.x;

  // ---- A fragments (latents rows, fp16) in registers + c = sum(l^2) ----
  half8 afrag[8];
  float c = 0.f;
  {
    int rowg = blk*64 + wave*16 + l15;
    const float* lr = latents + rowg*256;
#pragma unroll
    for (int ks = 0; ks < 8; ks++) {
      const float4* p = (const float4*)(lr + ks*32 + quad*8);
      float4 x = p[0], y = p[1];
      half8 h;
      h[0]=(_Float16)x.x; h[1]=(_Float16)x.y; h[2]=(_Float16)x.z; h[3]=(_Float16)x.w;
      h[4]=(_Float16)y.x; h[5]=(_Float16)y.y; h[6]=(_Float16)y.z; h[7]=(_Float16)y.w;
      afrag[ks] = h;
      c += x.x*x.x + x.y*x.y + x.z*x.z + x.w*x.w
         + y.x*y.x + y.y*y.y + y.z*y.z + y.w*y.w;
    }
    c += __shfl_xor(c, 16);
    c += __shfl_xor(c, 32);   // all quads summed: c for row (wave*16 + l15)
  }

  float m1[4], m2[4], ssum[4]; int i1[4];
#pragma unroll
  for (int r = 0; r < 4; r++) { m1[r]=1e30f; m2[r]=1e30f; ssum[r]=0.f; i1[r]=0; }
  floatx4 qacc[16];
  floatx4 zz = {0.f,0.f,0.f,0.f};
#pragma unroll
  for (int i = 0; i < 16; i++) qacc[i] = zz;

  float* Pp = dout + OFF_P;

  for (int kt = 0; kt < 32; kt++) {
    int k0 = kt*32;
    __syncthreads();   // protect LDS from previous iteration readers
    {
      // stage E tile: 32 rows x 256 d (fp16), 8 threads per row
      int r = tid >> 3, cb = (tid & 7)*4;
      const float4* src = (const float4*)(E16 + (size_t)(k0 + r)*256);
#pragma unroll
      for (int j = 0; j < 4; j++) {
        int ch = cb + j;
        float4 v = src[ch];
        *(float4*)(&ldsE[r*256 + ((ch ^ r)&31)*8]) = v;
      }
      // stage E^T tile: 256 d x 32 kl, one row per thread (contiguous 64B)
      const float4* src2 = (const float4*)(ETb + (size_t)kt*8192 + tid*32);
#pragma unroll
      for (int j = 0; j < 4; j++) {
        float4 v = src2[j];
        *(float4*)(&ldsET[tid*32 + (j ^ ((tid>>1)&3))*8]) = v;
      }
      if (tid < 32) lds_e2[tid] = e2g[k0 + tid];
    }
    __syncthreads();

    // ---- GEMM1: band rows (wave*16..+15) x 32 k-cols ----
    floatx4 sacc[2]; sacc[0] = zz; sacc[1] = zz;
#pragma unroll
    for (int ks = 0; ks < 8; ks++) {
#pragma unroll
      for (int nt = 0; nt < 2; nt++) {
        int r = nt*16 + l15;
        half8 b = *(const half8*)(&ldsE[r*256 + (((ks*4+quad) ^ r)&31)*8]);
        sacc[nt] = __builtin_amdgcn_mfma_f32_16x16x32_f16(afrag[ks], b, sacc[nt], 0, 0, 0);
      }
    }

    // ---- epilogue: v = e2 - 2*dot ; p = exp(-10 v) ----
#pragma unroll
    for (int nt = 0; nt < 2; nt++) {
      int kl = nt*16 + l15;
      int kcol = k0 + kl;
      float e2v = lds_e2[kl];
#pragma unroll
      for (int reg = 0; reg < 4; reg++) {
        float v = fmaf(-2.f, sacc[nt][reg], e2v);
        if (v < m1[reg]) { m2[reg] = m1[reg]; m1[reg] = v; i1[reg] = kcol; }
        else if (v < m2[reg]) m2[reg] = v;
        float pz = __expf(-10.f * v);
        ssum[reg] += pz;
        int rib = wave*16 + quad*4 + reg;
        Pp[(blk*64 + rib)*1024 + kcol] = pz;   // unnormalized, scaled later
        ldsA[rib*32 + (((kl>>3) ^ ((rib>>1)&3)))*8 + (kl&7)] = (_Float16)pz;
      }
    }
    __syncthreads();   // A-buf visible across waves

    // ---- GEMM2: O(64 x 256) += Ptile(64x32) * Etile(32x256); wave owns 64 d-cols ----
    half8 bp[4];
#pragma unroll
    for (int nt = 0; nt < 4; nt++) {
      int d = wave*64 + nt*16 + l15;
      bp[nt] = *(const half8*)(&ldsET[d*32 + (quad ^ ((d>>1)&3))*8]);
    }
#pragma unroll
    for (int mt = 0; mt < 4; mt++) {
      int rib = mt*16 + l15;
      half8 ap = *(const half8*)(&ldsA[rib*32 + (quad ^ ((rib>>1)&3))*8]);
#pragma unroll
      for (int nt = 0; nt < 4; nt++)
        qacc[mt*4+nt] = __builtin_amdgcn_mfma_f32_16x16x32_f16(ap, bp[nt], qacc[mt*4+nt], 0, 0, 0);
    }
  }

  // ---- row reductions across the 16 lanes (columns) of each quad ----
#pragma unroll
  for (int reg = 0; reg < 4; reg++) {
#pragma unroll
    for (int mbit = 1; mbit < 16; mbit <<= 1) {
      float om1 = __shfl_xor(m1[reg], mbit);
      int   oi1 = __shfl_xor(i1[reg], mbit);
      float om2 = __shfl_xor(m2[reg], mbit);
      float os  = __shfl_xor(ssum[reg], mbit);
      ssum[reg] += os;
      bool take = (om1 < m1[reg]) || (om1 == m1[reg] && oi1 < i1[reg]);
      float big = take ? m1[reg] : om1;
      if (take) { m1[reg] = om1; i1[reg] = oi1; }
      m2[reg] = fminf(fminf(m2[reg], om2), big);
    }
  }
#pragma unroll
  for (int reg = 0; reg < 4; reg++) {
    if (l15 == quad*4 + reg) {     // this lane's c matches row wave*16+l15
      int rib = wave*16 + quad*4 + reg;
      int rg = blk*64 + rib;
      float iv = 1.f / ssum[reg];
      lds_inv[rib] = iv;
      invg[rg] = iv;
      float md = c + m1[reg];
      mindg[rg] = md;
      atomicAdd(csum, md);
      dout[OFF_IDX + rg] = (float)i1[reg];
      if (m2[reg] - m1[reg] <= THETA) {
        int p = atomicAdd(cnt, 1);
        flag[p] = rg;
      }
    }
  }
  __syncthreads();

  // ---- Q epilogue: normalize, store, loss partial ----
  float ll = 0.f;
#pragma unroll
  for (int mt = 0; mt < 4; mt++) {
#pragma unroll
    for (int nt = 0; nt < 4; nt++) {
#pragma unroll
      for (int reg = 0; reg < 4; reg++) {
        int rib = mt*16 + quad*4 + reg;
        int dcol = wave*64 + nt*16 + l15;
        float q = qacc[mt*4+nt][reg] * lds_inv[rib];
        int rg = blk*64 + rib;
        dout[OFF_Q + rg*256 + dcol] = q;
        float lv = latents[rg*256 + dcol];
        float df = q - lv;
        ll = fmaf(df, df, ll);
      }
    }
  }
#pragma unroll
  for (int mbit = 1; mbit < 64; mbit <<= 1) ll += __shfl_xor(ll, mbit);
  if (lane == 0) lds_red[wave] = ll;
  __syncthreads();
  if (tid == 0) atomicAdd(lsum, lds_red[0]+lds_red[1]+lds_red[2]+lds_red[3]);
}

// scale P in place by 1/rowsum; accumulate column sums for entropy
__global__ void vq_scale(char* ws, float* __restrict__ dout) {
  const float* invg = (const float*)(ws + WS_INV);
  float* col = (float*)(ws + WS_COL);
  float* P = dout + OFF_P;
  int t = threadIdx.x, blk = blockIdx.x;
  float a0=0.f,a1=0.f,a2=0.f,a3=0.f;
  int base = blk*64;
  for (int r = 0; r < 64; r++) {
    float iv = invg[base + r];
    size_t off = (size_t)(base + r)*1024 + t*4;
    float p0 = P[off+0]*iv, p1 = P[off+1]*iv, p2 = P[off+2]*iv, p3 = P[off+3]*iv;
    P[off+0]=p0; P[off+1]=p1; P[off+2]=p2; P[off+3]=p3;
    a0+=p0; a1+=p1; a2+=p2; a3+=p3;
  }
  atomicAdd(&col[t*4+0], a0);
  atomicAdd(&col[t*4+1], a1);
  atomicAdd(&col[t*4+2], a2);
  atomicAdd(&col[t*4+3], a3);
}

// exact fp32 argmin for rows whose top-2 gap was within THETA
__global__ void vq_fallback(const float* __restrict__ latents, const float* __restrict__ emb,
                            char* ws, float* __restrict__ dout) {
  const float* e2g = (const float*)(ws + WS_E2);
  const int* flag = (const int*)(ws + WS_FLAG);
  const int* cnt = (const int*)(ws + WS_CNT);
  const float* mindg = (const float*)(ws + WS_MIND);
  float* csum = (float*)(ws + WS_CSUM);
  __shared__ float lrow[256];
  __shared__ float lsq[256];
  __shared__ float cshared;
  __shared__ float wv[4];
  __shared__ int wi[4];
  int tid = threadIdx.x;
  int n = *cnt;
  for (int it = blockIdx.x; it < n; it += gridDim.x) {
    int rg = flag[it];
    __syncthreads();
    float v = latents[rg*256 + tid];
    lrow[tid] = v; lsq[tid] = v*v;
    __syncthreads();
    if (tid == 0) cshared = np_pw128(lsq) + np_pw128(lsq+128);  // numpy-pairwise c
    __syncthreads();
    float c = cshared;
    float bv = 1e30f; int bi = 0;
    for (int kk = 0; kk < 4; kk++) {
      int k = kk*256 + tid;
      const float* er = emb + k*256;
      float dot = 0.f;
#pragma unroll 8
      for (int d = 0; d < 256; d++) dot = fmaf(lrow[d], er[d], dot);
      float dist = (c + e2g[k]) - 2.f*dot;   // reference op order
      if (dist < bv) { bv = dist; bi = k; }
    }
    int lane = tid & 63, wave = tid >> 6;
    for (int m = 1; m < 64; m <<= 1) {
      float ov = __shfl_xor(bv, m); int oi = __shfl_xor(bi, m);
      if (ov < bv || (ov == bv && oi < bi)) { bv = ov; bi = oi; }
    }
    if (lane == 0) { wv[wave] = bv; wi[wave] = bi; }
    __syncthreads();
    if (tid == 0) {
      for (int w = 1; w < 4; w++)
        if (wv[w] < bv || (wv[w] == bv && wi[w] < bi)) { bv = wv[w]; bi = wi[w]; }
      atomicAdd(csum, bv - mindg[rg]);
      dout[OFF_IDX + rg] = (float)bi;
    }
  }
}

__global__ void vq_gather(const float* __restrict__ emb, float* __restrict__ dout) {
  int row = blockIdx.x;
  int d = threadIdx.x;
  int idx = (int)dout[OFF_IDX + row];
  dout[OFF_HQ + row*256 + d] = emb[idx*256 + d];
}

__global__ void vq_finalize(char* ws, float* __restrict__ dout) {
  const float* col = (const float*)(ws + WS_COL);
  int tid = threadIdx.x;
  float a = col[tid] * (1.f/65536.f);
  float term = a * logf(a + 1e-10f);
  for (int m = 1; m < 64; m <<= 1) term += __shfl_xor(term, m);
  __shared__ float wr[16];
  int lane = tid & 63, wave = tid >> 6;
  if (lane == 0) wr[wave] = term;
  __syncthreads();
  if (tid == 0) {
    float s = 0.f;
    for (int w = 0; w < 16; w++) s += wr[w];
    dout[OFF_ENT] = -s;
    dout[OFF_LOSS] = 1.25f * (*(float*)(ws + WS_LSUM)) / (65536.f*256.f);
    dout[OFF_CM] = (*(float*)(ws + WS_CSUM)) * (1.f/65536.f);
  }
}

extern "C" void kernel_launch(void* const* d_in, const int* in_sizes, int n_in,
                              void* d_out, int out_size, void* d_ws, size_t ws_size,
                              hipStream_t stream) {
  (void)in_sizes; (void)n_in; (void)out_size; (void)ws_size;
  const float* latents = (const float*)d_in[0];
  const float* emb = (const float*)d_in[1];
  float* dout = (float*)d_out;
  char* ws = (char*)d_ws;

  vq_prep<<<1024, 256, 0, stream>>>(emb, ws);
  vq_main<<<1024, 256, 0, stream>>>(latents, ws, dout);
  vq_scale<<<1024, 256, 0, stream>>>(ws, dout);
  vq_fallback<<<1024, 256, 0, stream>>>(latents, emb, ws, dout);
  vq_gather<<<65536, 256, 0, stream>>>(emb, dout);
  vq_finalize<<<1, 1024, 0, stream>>>(ws, dout);
}